// Round 1
// baseline (280.038 us; speedup 1.0000x reference)
//
#include <hip/hip_runtime.h>
#include <hip/hip_bf16.h>
#include <stdint.h>

#define T_DIM 256
#define U_DIM 64
#define D_DIM 512
#define NIN 512
#define NV 4096

typedef __bf16 bf16x8 __attribute__((ext_vector_type(8)));
typedef float f32x4 __attribute__((ext_vector_type(4)));

static __device__ __forceinline__ unsigned short f2bf(float x) {
  union { float f; unsigned int u; } v; v.f = x;
  unsigned int r = v.u + 0x7FFFu + ((v.u >> 16) & 1u);
  return (unsigned short)(r >> 16);
}

static __device__ __forceinline__ void gload_lds16(const unsigned short* g, unsigned short* l) {
  __builtin_amdgcn_global_load_lds(
      (__attribute__((address_space(1))) void*)(unsigned short*)g,
      (__attribute__((address_space(3))) void*)l, 16, 0, 0);
}

// ---------------- W2 f32 -> bf16 ----------------
__global__ __launch_bounds__(256) void convert_w2_kernel(const float* __restrict__ W2,
                                                         unsigned short* __restrict__ W2b) {
  int q = blockIdx.x * 256 + threadIdx.x;  // 262144 threads, 8 elems each
  const float4 v0 = *(const float4*)(W2 + (size_t)q * 8);
  const float4 v1 = *(const float4*)(W2 + (size_t)q * 8 + 4);
  union { unsigned short s[8]; uint4 u; } o;
  o.s[0] = f2bf(v0.x); o.s[1] = f2bf(v0.y); o.s[2] = f2bf(v0.z); o.s[3] = f2bf(v0.w);
  o.s[4] = f2bf(v1.x); o.s[5] = f2bf(v1.y); o.s[6] = f2bf(v1.z); o.s[7] = f2bf(v1.w);
  *(uint4*)(W2b + (size_t)q * 8) = o.u;
}

// ---------------- proj: ep = enc @ We^T ; dp = dec @ Wd^T + b1 ----------------
// grid = 20 blocks: tile_m 0..3 -> enc (512 rows), tile_m 4 -> dec (128 rows); tile_n 0..3
__global__ __launch_bounds__(256) void proj_kernel(const float* __restrict__ enc,
                                                   const float* __restrict__ dec,
                                                   const float* __restrict__ W1,
                                                   const float* __restrict__ b1,
                                                   float* __restrict__ ep,
                                                   float* __restrict__ dp) {
  __shared__ unsigned short As[128 * 32];
  __shared__ unsigned short Bs[128 * 32];
  const int tid = threadIdx.x;
  const int tile_m = blockIdx.x >> 2;
  const int tile_n = blockIdx.x & 3;
  const bool is_dec = (tile_m == 4);
  const float* X = is_dec ? dec : enc;
  const int xrow0 = is_dec ? 0 : tile_m * 128;
  const int wcol0 = is_dec ? D_DIM : 0;
  float* outp = is_dec ? dp : ep;

  const int lane = tid & 63;
  const int wv = tid >> 6;
  const int wr = wv >> 1, wc = wv & 1;

  const int arow = tid >> 1;           // 0..127
  const int acol = (tid & 1) * 16;     // 0 or 16

  f32x4 acc[4][4] = {};

  const float* pa = X + (size_t)(xrow0 + arow) * D_DIM + acol;
  const float* pb = W1 + (size_t)(tile_n * 128 + arow) * (2 * D_DIM) + wcol0 + acol;

  for (int k0 = 0; k0 < D_DIM; k0 += 32) {
    float4 av0 = *(const float4*)(pa + k0);
    float4 av1 = *(const float4*)(pa + k0 + 4);
    float4 av2 = *(const float4*)(pa + k0 + 8);
    float4 av3 = *(const float4*)(pa + k0 + 12);
    float4 bv0 = *(const float4*)(pb + k0);
    float4 bv1 = *(const float4*)(pb + k0 + 4);
    float4 bv2 = *(const float4*)(pb + k0 + 8);
    float4 bv3 = *(const float4*)(pb + k0 + 12);
    __syncthreads();  // previous iteration's reads done before overwrite
    union { unsigned short s[8]; uint4 u; } u0, u1, w0, w1;
    u0.s[0] = f2bf(av0.x); u0.s[1] = f2bf(av0.y); u0.s[2] = f2bf(av0.z); u0.s[3] = f2bf(av0.w);
    u0.s[4] = f2bf(av1.x); u0.s[5] = f2bf(av1.y); u0.s[6] = f2bf(av1.z); u0.s[7] = f2bf(av1.w);
    u1.s[0] = f2bf(av2.x); u1.s[1] = f2bf(av2.y); u1.s[2] = f2bf(av2.z); u1.s[3] = f2bf(av2.w);
    u1.s[4] = f2bf(av3.x); u1.s[5] = f2bf(av3.y); u1.s[6] = f2bf(av3.z); u1.s[7] = f2bf(av3.w);
    w0.s[0] = f2bf(bv0.x); w0.s[1] = f2bf(bv0.y); w0.s[2] = f2bf(bv0.z); w0.s[3] = f2bf(bv0.w);
    w0.s[4] = f2bf(bv1.x); w0.s[5] = f2bf(bv1.y); w0.s[6] = f2bf(bv1.z); w0.s[7] = f2bf(bv1.w);
    w1.s[0] = f2bf(bv2.x); w1.s[1] = f2bf(bv2.y); w1.s[2] = f2bf(bv2.z); w1.s[3] = f2bf(bv2.w);
    w1.s[4] = f2bf(bv3.x); w1.s[5] = f2bf(bv3.y); w1.s[6] = f2bf(bv3.z); w1.s[7] = f2bf(bv3.w);
    *(uint4*)&As[arow * 32 + acol] = u0.u;
    *(uint4*)&As[arow * 32 + acol + 8] = u1.u;
    *(uint4*)&Bs[arow * 32 + acol] = w0.u;
    *(uint4*)&Bs[arow * 32 + acol + 8] = w1.u;
    __syncthreads();
    bf16x8 af[4], bff[4];
#pragma unroll
    for (int mi = 0; mi < 4; ++mi)
      af[mi] = *(const bf16x8*)&As[(wr * 64 + mi * 16 + (lane & 15)) * 32 + (lane >> 4) * 8];
#pragma unroll
    for (int ni = 0; ni < 4; ++ni)
      bff[ni] = *(const bf16x8*)&Bs[(wc * 64 + ni * 16 + (lane & 15)) * 32 + (lane >> 4) * 8];
#pragma unroll
    for (int mi = 0; mi < 4; ++mi)
#pragma unroll
      for (int ni = 0; ni < 4; ++ni)
        acc[mi][ni] = __builtin_amdgcn_mfma_f32_16x16x32_bf16(af[mi], bff[ni], acc[mi][ni], 0, 0, 0);
  }

  float b1v[4];
#pragma unroll
  for (int ni = 0; ni < 4; ++ni) {
    int col = tile_n * 128 + wc * 64 + ni * 16 + (lane & 15);
    b1v[ni] = is_dec ? b1[col] : 0.0f;
  }
#pragma unroll
  for (int mi = 0; mi < 4; ++mi) {
#pragma unroll
    for (int r = 0; r < 4; ++r) {
      int row = xrow0 + wr * 64 + mi * 16 + ((lane >> 4) << 2) + r;
      float* po = outp + (size_t)row * NIN + tile_n * 128 + wc * 64 + (lane & 15);
#pragma unroll
      for (int ni = 0; ni < 4; ++ni) po[ni * 16] = acc[mi][ni][r] + b1v[ni];
    }
  }
}

// ---------------- H = tanh(ep[bt] + dp[bu]) -> bf16 ----------------
__global__ __launch_bounds__(256) void h_kernel(const float* __restrict__ ep,
                                                const float* __restrict__ dp,
                                                unsigned short* __restrict__ Hb) {
  int q = blockIdx.x * 256 + threadIdx.x;  // 2097152 threads, 8 elems each
  int m = q >> 6;                          // row in H (0..32767), m = (b*T+t)*U+u
  int i0 = (q & 63) << 3;
  const float* pe = ep + (size_t)(m >> 6) * NIN + i0;                          // bt = m/U
  const float* pd = dp + (size_t)((m >> 14) * U_DIM + (m & 63)) * NIN + i0;    // b*U+u
  float4 e0 = *(const float4*)pe;
  float4 e1 = *(const float4*)(pe + 4);
  float4 d0 = *(const float4*)pd;
  float4 d1 = *(const float4*)(pd + 4);
  float x[8] = { e0.x + d0.x, e0.y + d0.y, e0.z + d0.z, e0.w + d0.w,
                 e1.x + d1.x, e1.y + d1.y, e1.z + d1.z, e1.w + d1.w };
  union { unsigned short s[8]; uint4 u; } o;
#pragma unroll
  for (int j = 0; j < 8; ++j) {
    float ex = __expf(2.0f * x[j]);
    float t = 1.0f - 2.0f / (ex + 1.0f);
    o.s[j] = f2bf(t);
  }
  *(uint4*)(Hb + (size_t)q * 8) = o.u;
}

// ---------------- main GEMM: out = H @ W2b^T + b2 ----------------
// M=32768, N=4096, K=512; 128x128 tile, BK=32, 4 waves, m97 structure
__global__ __launch_bounds__(256) void gemm_kernel(const unsigned short* __restrict__ Hb,
                                                   const unsigned short* __restrict__ W2b,
                                                   const float* __restrict__ b2,
                                                   float* __restrict__ out) {
  __shared__ unsigned short As[128 * 32];
  __shared__ unsigned short Bs[128 * 32];
  const int tid = threadIdx.x;
  const int bid = blockIdx.x;
  // XCD-aware swizzle: 8192 blocks, 8 XCDs, chunk = 1024
  const int wg = ((bid & 7) << 10) | (bid >> 3);
  const int tile_n = wg & 31;
  const int tile_m = wg >> 5;
  const int m0 = tile_m * 128, n0 = tile_n * 128;

  const int lane = tid & 63;
  const int wv = tid >> 6;
  const int wr = wv >> 1, wc = wv & 1;

  f32x4 acc[4][4] = {};

  const int sr = lane >> 2;         // 0..15
  const int sc = (lane & 3) * 8;    // elem col
  const unsigned short* gA0 = Hb + (size_t)(m0 + wv * 32 + sr) * 512 + sc;
  const unsigned short* gA1 = gA0 + 16 * 512;
  const unsigned short* gB0 = W2b + (size_t)(n0 + wv * 32 + sr) * 512 + sc;
  const unsigned short* gB1 = gB0 + 16 * 512;
  unsigned short* lA0 = As + (wv * 32) * 32;
  unsigned short* lA1 = As + (wv * 32 + 16) * 32;
  unsigned short* lB0 = Bs + (wv * 32) * 32;
  unsigned short* lB1 = Bs + (wv * 32 + 16) * 32;

  for (int k0 = 0; k0 < 512; k0 += 32) {
    __syncthreads();
    gload_lds16(gA0 + k0, lA0);
    gload_lds16(gA1 + k0, lA1);
    gload_lds16(gB0 + k0, lB0);
    gload_lds16(gB1 + k0, lB1);
    __syncthreads();
    bf16x8 af[4], bff[4];
#pragma unroll
    for (int mi = 0; mi < 4; ++mi)
      af[mi] = *(const bf16x8*)&As[(wr * 64 + mi * 16 + (lane & 15)) * 32 + (lane >> 4) * 8];
#pragma unroll
    for (int ni = 0; ni < 4; ++ni)
      bff[ni] = *(const bf16x8*)&Bs[(wc * 64 + ni * 16 + (lane & 15)) * 32 + (lane >> 4) * 8];
#pragma unroll
    for (int mi = 0; mi < 4; ++mi)
#pragma unroll
      for (int ni = 0; ni < 4; ++ni)
        acc[mi][ni] = __builtin_amdgcn_mfma_f32_16x16x32_bf16(af[mi], bff[ni], acc[mi][ni], 0, 0, 0);
  }

  float b2v[4];
#pragma unroll
  for (int ni = 0; ni < 4; ++ni) b2v[ni] = b2[n0 + wc * 64 + ni * 16 + (lane & 15)];
#pragma unroll
  for (int mi = 0; mi < 4; ++mi) {
#pragma unroll
    for (int r = 0; r < 4; ++r) {
      int row = m0 + wr * 64 + mi * 16 + ((lane >> 4) << 2) + r;
      float* po = out + (size_t)row * NV + n0 + wc * 64 + (lane & 15);
#pragma unroll
      for (int ni = 0; ni < 4; ++ni) po[ni * 16] = acc[mi][ni][r] + b2v[ni];
    }
  }
}

extern "C" void kernel_launch(void* const* d_in, const int* in_sizes, int n_in,
                              void* d_out, int out_size, void* d_ws, size_t ws_size,
                              hipStream_t stream) {
  const float* enc = (const float*)d_in[0];
  const float* dec = (const float*)d_in[1];
  const float* W1  = (const float*)d_in[2];
  const float* b1  = (const float*)d_in[3];
  const float* W2  = (const float*)d_in[4];
  const float* b2  = (const float*)d_in[5];
  float* out = (float*)d_out;

  char* ws = (char*)d_ws;
  unsigned short* W2b = (unsigned short*)(ws);                // 4 MB
  float* ep = (float*)(ws + 4194304);                         // 1 MB (512x512)
  float* dp = (float*)(ws + 5242880);                         // 256 KB (128x512)
  unsigned short* Hb = (unsigned short*)(ws + 5505024);       // 32 MB (32768x512)

  hipLaunchKernelGGL(convert_w2_kernel, dim3(1024), dim3(256), 0, stream, W2, W2b);
  hipLaunchKernelGGL(proj_kernel, dim3(20), dim3(256), 0, stream, enc, dec, W1, b1, ep, dp);
  hipLaunchKernelGGL(h_kernel, dim3(8192), dim3(256), 0, stream, ep, dp, Hb);
  hipLaunchKernelGGL(gemm_kernel, dim3(8192), dim3(256), 0, stream, Hb, W2b, b2, out);
}

// Round 2
// 254.070 us; speedup vs baseline: 1.1022x; 1.1022x over previous
//
#include <hip/hip_runtime.h>
#include <hip/hip_bf16.h>
#include <stdint.h>

#define T_DIM 256
#define U_DIM 64
#define D_DIM 512
#define NIN 512
#define NV 4096

typedef __bf16 bf16x8 __attribute__((ext_vector_type(8)));
typedef float f32x4 __attribute__((ext_vector_type(4)));

static __device__ __forceinline__ unsigned short f2bf(float x) {
  union { float f; unsigned int u; } v; v.f = x;
  unsigned int r = v.u + 0x7FFFu + ((v.u >> 16) & 1u);
  return (unsigned short)(r >> 16);
}

static __device__ __forceinline__ void gload_lds16(const unsigned short* g, void* l) {
  __builtin_amdgcn_global_load_lds(
      (__attribute__((address_space(1))) void*)(unsigned short*)g,
      (__attribute__((address_space(3))) void*)l, 16, 0, 0);
}

// ---------------- W2 f32 -> bf16 ----------------
__global__ __launch_bounds__(256) void convert_w2_kernel(const float* __restrict__ W2,
                                                         unsigned short* __restrict__ W2b) {
  int q = blockIdx.x * 256 + threadIdx.x;
  const float4 v0 = *(const float4*)(W2 + (size_t)q * 8);
  const float4 v1 = *(const float4*)(W2 + (size_t)q * 8 + 4);
  union { unsigned short s[8]; uint4 u; } o;
  o.s[0] = f2bf(v0.x); o.s[1] = f2bf(v0.y); o.s[2] = f2bf(v0.z); o.s[3] = f2bf(v0.w);
  o.s[4] = f2bf(v1.x); o.s[5] = f2bf(v1.y); o.s[6] = f2bf(v1.z); o.s[7] = f2bf(v1.w);
  *(uint4*)(W2b + (size_t)q * 8) = o.u;
}

// ---------------- proj: ep = enc @ We^T ; dp = dec @ Wd^T + b1 ----------------
__global__ __launch_bounds__(256) void proj_kernel(const float* __restrict__ enc,
                                                   const float* __restrict__ dec,
                                                   const float* __restrict__ W1,
                                                   const float* __restrict__ b1,
                                                   float* __restrict__ ep,
                                                   float* __restrict__ dp) {
  __shared__ unsigned short As[128 * 32];
  __shared__ unsigned short Bs[128 * 32];
  const int tid = threadIdx.x;
  const int tile_m = blockIdx.x >> 2;
  const int tile_n = blockIdx.x & 3;
  const bool is_dec = (tile_m == 4);
  const float* X = is_dec ? dec : enc;
  const int xrow0 = is_dec ? 0 : tile_m * 128;
  const int wcol0 = is_dec ? D_DIM : 0;
  float* outp = is_dec ? dp : ep;

  const int lane = tid & 63;
  const int wv = tid >> 6;
  const int wr = wv >> 1, wc = wv & 1;

  const int arow = tid >> 1;
  const int acol = (tid & 1) * 16;

  f32x4 acc[4][4] = {};

  const float* pa = X + (size_t)(xrow0 + arow) * D_DIM + acol;
  const float* pb = W1 + (size_t)(tile_n * 128 + arow) * (2 * D_DIM) + wcol0 + acol;

  for (int k0 = 0; k0 < D_DIM; k0 += 32) {
    float4 av0 = *(const float4*)(pa + k0);
    float4 av1 = *(const float4*)(pa + k0 + 4);
    float4 av2 = *(const float4*)(pa + k0 + 8);
    float4 av3 = *(const float4*)(pa + k0 + 12);
    float4 bv0 = *(const float4*)(pb + k0);
    float4 bv1 = *(const float4*)(pb + k0 + 4);
    float4 bv2 = *(const float4*)(pb + k0 + 8);
    float4 bv3 = *(const float4*)(pb + k0 + 12);
    __syncthreads();
    union { unsigned short s[8]; uint4 u; } u0, u1, w0, w1;
    u0.s[0] = f2bf(av0.x); u0.s[1] = f2bf(av0.y); u0.s[2] = f2bf(av0.z); u0.s[3] = f2bf(av0.w);
    u0.s[4] = f2bf(av1.x); u0.s[5] = f2bf(av1.y); u0.s[6] = f2bf(av1.z); u0.s[7] = f2bf(av1.w);
    u1.s[0] = f2bf(av2.x); u1.s[1] = f2bf(av2.y); u1.s[2] = f2bf(av2.z); u1.s[3] = f2bf(av2.w);
    u1.s[4] = f2bf(av3.x); u1.s[5] = f2bf(av3.y); u1.s[6] = f2bf(av3.z); u1.s[7] = f2bf(av3.w);
    w0.s[0] = f2bf(bv0.x); w0.s[1] = f2bf(bv0.y); w0.s[2] = f2bf(bv0.z); w0.s[3] = f2bf(bv0.w);
    w0.s[4] = f2bf(bv1.x); w0.s[5] = f2bf(bv1.y); w0.s[6] = f2bf(bv1.z); w0.s[7] = f2bf(bv1.w);
    w1.s[0] = f2bf(bv2.x); w1.s[1] = f2bf(bv2.y); w1.s[2] = f2bf(bv2.z); w1.s[3] = f2bf(bv2.w);
    w1.s[4] = f2bf(bv3.x); w1.s[5] = f2bf(bv3.y); w1.s[6] = f2bf(bv3.z); w1.s[7] = f2bf(bv3.w);
    *(uint4*)&As[arow * 32 + acol] = u0.u;
    *(uint4*)&As[arow * 32 + acol + 8] = u1.u;
    *(uint4*)&Bs[arow * 32 + acol] = w0.u;
    *(uint4*)&Bs[arow * 32 + acol + 8] = w1.u;
    __syncthreads();
    bf16x8 af[4], bff[4];
#pragma unroll
    for (int mi = 0; mi < 4; ++mi)
      af[mi] = *(const bf16x8*)&As[(wr * 64 + mi * 16 + (lane & 15)) * 32 + (lane >> 4) * 8];
#pragma unroll
    for (int ni = 0; ni < 4; ++ni)
      bff[ni] = *(const bf16x8*)&Bs[(wc * 64 + ni * 16 + (lane & 15)) * 32 + (lane >> 4) * 8];
#pragma unroll
    for (int mi = 0; mi < 4; ++mi)
#pragma unroll
      for (int ni = 0; ni < 4; ++ni)
        acc[mi][ni] = __builtin_amdgcn_mfma_f32_16x16x32_bf16(af[mi], bff[ni], acc[mi][ni], 0, 0, 0);
  }

  float b1v[4];
#pragma unroll
  for (int ni = 0; ni < 4; ++ni) {
    int col = tile_n * 128 + wc * 64 + ni * 16 + (lane & 15);
    b1v[ni] = is_dec ? b1[col] : 0.0f;
  }
#pragma unroll
  for (int mi = 0; mi < 4; ++mi) {
#pragma unroll
    for (int r = 0; r < 4; ++r) {
      int row = xrow0 + wr * 64 + mi * 16 + ((lane >> 4) << 2) + r;
      float* po = outp + (size_t)row * NIN + tile_n * 128 + wc * 64 + (lane & 15);
#pragma unroll
      for (int ni = 0; ni < 4; ++ni) po[ni * 16] = acc[mi][ni][r] + b1v[ni];
    }
  }
}

// ---------------- H = tanh(ep[bt] + dp[bu]) -> bf16 ----------------
__global__ __launch_bounds__(256) void h_kernel(const float* __restrict__ ep,
                                                const float* __restrict__ dp,
                                                unsigned short* __restrict__ Hb) {
  int q = blockIdx.x * 256 + threadIdx.x;
  int m = q >> 6;
  int i0 = (q & 63) << 3;
  const float* pe = ep + (size_t)(m >> 6) * NIN + i0;
  const float* pd = dp + (size_t)((m >> 14) * U_DIM + (m & 63)) * NIN + i0;
  float4 e0 = *(const float4*)pe;
  float4 e1 = *(const float4*)(pe + 4);
  float4 d0 = *(const float4*)pd;
  float4 d1 = *(const float4*)(pd + 4);
  float x[8] = { e0.x + d0.x, e0.y + d0.y, e0.z + d0.z, e0.w + d0.w,
                 e1.x + d1.x, e1.y + d1.y, e1.z + d1.z, e1.w + d1.w };
  union { unsigned short s[8]; uint4 u; } o;
#pragma unroll
  for (int j = 0; j < 8; ++j) {
    float ex = __expf(2.0f * x[j]);
    float t = 1.0f - 2.0f / (ex + 1.0f);
    o.s[j] = f2bf(t);
  }
  *(uint4*)(Hb + (size_t)q * 8) = o.u;
}

// ---------------- main GEMM: out = H @ W2b^T + b2 ----------------
// 256x256 tile, BK=64 (two k-halves of 32), 8 waves (2x4), 8-phase counted-vmcnt
// schedule (T2+T3+T4+T5). LDS 128 KiB: A[2buf][2kh][256x32] + B same.
// Swizzle: sigma(o) = o ^ ((row&3)<<4) realized via pre-swizzled global source
// (linear gload_lds dest) + swizzled ds_read addr -> conflict-free b128 reads.
__global__ __launch_bounds__(512, 2) void gemm256_kernel(const unsigned short* __restrict__ Hb,
                                                         const unsigned short* __restrict__ W2b,
                                                         const float* __restrict__ b2,
                                                         float* __restrict__ out) {
  __shared__ __align__(16) char smem[131072];
  const int tid = threadIdx.x;
  const int bid = blockIdx.x;
  // XCD swizzle: 2048 blocks, 8 XCDs, 256 per XCD
  const int swz = ((bid & 7) << 8) | (bid >> 3);
  const int tile_n = swz & 15, tile_m = swz >> 4;
  const int m0 = tile_m * 256, n0 = tile_n * 256;
  const int lane = tid & 63, w = tid >> 6;
  const int wr = w >> 2, wc = w & 3;

  // staging source (pre-swizzled): row = chunk*16 + (lane>>2), seg = (lane&3)^((lane>>2)&3)
  const int srow0 = (w << 4) + (lane >> 2);
  const int segp = (((lane & 3) ^ ((lane >> 2) & 3)) << 3);
  const unsigned short* pA0 = Hb + (size_t)(m0 + srow0) * 512 + segp;
  const unsigned short* pA1 = pA0 + 128 * 512;
  const unsigned short* pB0 = W2b + (size_t)(n0 + srow0) * 512 + segp;
  const unsigned short* pB1 = pB0 + 128 * 512;
  const int dstOff = (w << 10) + (lane << 4);  // linear LDS dest, chunk*1024 + lane*16
  // swizzled ds_read lane offset: row (lane&15), seg (lane>>4)^(lane&3)
  const int laneA = ((lane & 15) << 6) + ((((lane >> 4) ^ (lane & 3)) & 3) << 4);
  const int wrOff = wr << 13;  // wr*8192 (A row block)
  const int wcOff = wc << 12;  // wc*4096 (B row block)

  f32x4 acc[8][4] = {};
  bf16x8 af[8], bq0, bq1;

#define STAGE_A(BUF, KH, T) do { \
    gload_lds16(pA0 + (T) * 64 + (KH) * 32, smem + (BUF) * 32768 + (KH) * 16384 + dstOff); \
    gload_lds16(pA1 + (T) * 64 + (KH) * 32, smem + (BUF) * 32768 + (KH) * 16384 + 8192 + dstOff); \
  } while (0)
#define STAGE_B(BUF, KH, T) do { \
    gload_lds16(pB0 + (T) * 64 + (KH) * 32, smem + 65536 + (BUF) * 32768 + (KH) * 16384 + dstOff); \
    gload_lds16(pB1 + (T) * 64 + (KH) * 32, smem + 65536 + (BUF) * 32768 + (KH) * 16384 + 8192 + dstOff); \
  } while (0)
#define DS_A(BUF, KH, MI) (*(const bf16x8*)(smem + (BUF) * 32768 + (KH) * 16384 + wrOff + (MI) * 1024 + laneA))
#define DS_B(BUF, KH, NI) (*(const bf16x8*)(smem + 65536 + (BUF) * 32768 + (KH) * 16384 + wcOff + (NI) * 1024 + laneA))
#define LD_A(BUF, KH) do { \
    _Pragma("unroll") for (int mi = 0; mi < 8; ++mi) af[mi] = DS_A(BUF, KH, mi); \
  } while (0)
#define QUAD(NH) do { \
    __builtin_amdgcn_s_setprio(1); \
    _Pragma("unroll") for (int mi = 0; mi < 8; ++mi) { \
      acc[mi][2 * (NH)]     = __builtin_amdgcn_mfma_f32_16x16x32_bf16(af[mi], bq0, acc[mi][2 * (NH)], 0, 0, 0); \
      acc[mi][2 * (NH) + 1] = __builtin_amdgcn_mfma_f32_16x16x32_bf16(af[mi], bq1, acc[mi][2 * (NH) + 1], 0, 0, 0); \
    } \
    __builtin_amdgcn_s_setprio(0); \
  } while (0)
#define BAR() __builtin_amdgcn_s_barrier()
#define LGKM0() asm volatile("s_waitcnt lgkmcnt(0)" ::: "memory")
#define VMCNT4() asm volatile("s_waitcnt vmcnt(4)" ::: "memory")
#define VMCNT0() asm volatile("s_waitcnt vmcnt(0)" ::: "memory")

  // prologue: tile0 (all 4 halves, buf0) + tile1 A-k0/B-k0 (buf1); 12 loads
  STAGE_A(0, 0, 0); STAGE_A(0, 1, 0); STAGE_B(0, 0, 0); STAGE_B(0, 1, 0);
  STAGE_A(1, 0, 1); STAGE_B(1, 0, 1);
  VMCNT4();  // tile0's 8 loads landed (<=4 of tile1's outstanding)
  BAR();

  // steady state: iterations i=0..2 (tiles 2i,2i+1), stage tiles 2i+1..2i+3
  for (int i = 0; i < 3; ++i) {
    const int t1 = 2 * i + 1, t2 = 2 * i + 2, t3 = 2 * i + 3;
    // P1: compute tile2i (buf0,kh0,nh0); stage t1.A-k1 -> buf1
    LD_A(0, 0); bq0 = DS_B(0, 0, 0); bq1 = DS_B(0, 0, 1);
    STAGE_A(1, 1, t1);
    BAR(); LGKM0(); QUAD(0); BAR();
    // P2: (kh0,nh1); stage t1.B-k1
    bq0 = DS_B(0, 0, 2); bq1 = DS_B(0, 0, 3);
    STAGE_B(1, 1, t1);
    BAR(); LGKM0(); QUAD(1); BAR();
    // P3: (kh1,nh0); stage t2.A-k0 -> buf0
    LD_A(0, 1); bq0 = DS_B(0, 1, 0); bq1 = DS_B(0, 1, 1);
    STAGE_A(0, 0, t2);
    BAR(); LGKM0(); QUAD(0); BAR();
    // P4: (kh1,nh1); stage t2.B-k0; counted vmcnt
    bq0 = DS_B(0, 1, 2); bq1 = DS_B(0, 1, 3);
    STAGE_B(0, 0, t2);
    VMCNT4();
    BAR(); LGKM0(); QUAD(1); BAR();
    // P5: compute tile2i+1 (buf1,kh0,nh0); stage t2.A-k1
    LD_A(1, 0); bq0 = DS_B(1, 0, 0); bq1 = DS_B(1, 0, 1);
    STAGE_A(0, 1, t2);
    BAR(); LGKM0(); QUAD(0); BAR();
    // P6: (kh0,nh1); stage t2.B-k1
    bq0 = DS_B(1, 0, 2); bq1 = DS_B(1, 0, 3);
    STAGE_B(0, 1, t2);
    BAR(); LGKM0(); QUAD(1); BAR();
    // P7: (kh1,nh0); stage t3.A-k0 -> buf1
    LD_A(1, 1); bq0 = DS_B(1, 1, 0); bq1 = DS_B(1, 1, 1);
    STAGE_A(1, 0, t3);
    BAR(); LGKM0(); QUAD(0); BAR();
    // P8: (kh1,nh1); stage t3.B-k0; counted vmcnt
    bq0 = DS_B(1, 1, 2); bq1 = DS_B(1, 1, 3);
    STAGE_B(1, 0, t3);
    VMCNT4();
    BAR(); LGKM0(); QUAD(1); BAR();
  }

  // tail: i=3 (tiles 6,7); only t7.A-k1/B-k1 remain to stage
  LD_A(0, 0); bq0 = DS_B(0, 0, 0); bq1 = DS_B(0, 0, 1);
  STAGE_A(1, 1, 7);
  BAR(); LGKM0(); QUAD(0); BAR();
  bq0 = DS_B(0, 0, 2); bq1 = DS_B(0, 0, 3);
  STAGE_B(1, 1, 7);
  BAR(); LGKM0(); QUAD(1); BAR();
  LD_A(0, 1); bq0 = DS_B(0, 1, 0); bq1 = DS_B(0, 1, 1);
  BAR(); LGKM0(); QUAD(0); BAR();
  bq0 = DS_B(0, 1, 2); bq1 = DS_B(0, 1, 3);
  VMCNT0();
  BAR(); LGKM0(); QUAD(1); BAR();
  LD_A(1, 0); bq0 = DS_B(1, 0, 0); bq1 = DS_B(1, 0, 1);
  BAR(); LGKM0(); QUAD(0); BAR();
  bq0 = DS_B(1, 0, 2); bq1 = DS_B(1, 0, 3);
  BAR(); LGKM0(); QUAD(1); BAR();
  LD_A(1, 1); bq0 = DS_B(1, 1, 0); bq1 = DS_B(1, 1, 1);
  BAR(); LGKM0(); QUAD(0); BAR();
  bq0 = DS_B(1, 1, 2); bq1 = DS_B(1, 1, 3);
  BAR(); LGKM0(); QUAD(1);

  // epilogue: C = acc + b2
  float b2v[4];
#pragma unroll
  for (int ni = 0; ni < 4; ++ni) b2v[ni] = b2[n0 + wc * 64 + ni * 16 + (lane & 15)];
#pragma unroll
  for (int mi = 0; mi < 8; ++mi) {
#pragma unroll
    for (int r = 0; r < 4; ++r) {
      int row = m0 + wr * 128 + mi * 16 + ((lane >> 4) << 2) + r;
      float* po = out + (size_t)row * NV + n0 + wc * 64 + (lane & 15);
#pragma unroll
      for (int ni = 0; ni < 4; ++ni) po[ni * 16] = acc[mi][ni][r] + b2v[ni];
    }
  }
#undef STAGE_A
#undef STAGE_B
#undef DS_A
#undef DS_B
#undef LD_A
#undef QUAD
#undef BAR
#undef LGKM0
#undef VMCNT4
#undef VMCNT0
}

extern "C" void kernel_launch(void* const* d_in, const int* in_sizes, int n_in,
                              void* d_out, int out_size, void* d_ws, size_t ws_size,
                              hipStream_t stream) {
  const float* enc = (const float*)d_in[0];
  const float* dec = (const float*)d_in[1];
  const float* W1  = (const float*)d_in[2];
  const float* b1  = (const float*)d_in[3];
  const float* W2  = (const float*)d_in[4];
  const float* b2  = (const float*)d_in[5];
  float* out = (float*)d_out;

  char* ws = (char*)d_ws;
  unsigned short* W2b = (unsigned short*)(ws);                // 4 MB
  float* ep = (float*)(ws + 4194304);                         // 1 MB (512x512)
  float* dp = (float*)(ws + 5242880);                         // 256 KB (128x512)
  unsigned short* Hb = (unsigned short*)(ws + 5505024);       // 32 MB (32768x512)

  hipLaunchKernelGGL(convert_w2_kernel, dim3(1024), dim3(256), 0, stream, W2, W2b);
  hipLaunchKernelGGL(proj_kernel, dim3(20), dim3(256), 0, stream, enc, dec, W1, b1, ep, dp);
  hipLaunchKernelGGL(h_kernel, dim3(8192), dim3(256), 0, stream, ep, dp, Hb);
  hipLaunchKernelGGL(gemm256_kernel, dim3(2048), dim3(512), 0, stream, Hb, W2b, b2, out);
}

// Round 3
// 241.473 us; speedup vs baseline: 1.1597x; 1.0522x over previous
//
#include <hip/hip_runtime.h>
#include <hip/hip_bf16.h>
#include <stdint.h>

#define T_DIM 256
#define U_DIM 64
#define D_DIM 512
#define NIN 512
#define NV 4096

typedef __bf16 bf16x8 __attribute__((ext_vector_type(8)));
typedef float f32x4 __attribute__((ext_vector_type(4)));

static __device__ __forceinline__ unsigned short f2bf(float x) {
  union { float f; unsigned int u; } v; v.f = x;
  unsigned int r = v.u + 0x7FFFu + ((v.u >> 16) & 1u);
  return (unsigned short)(r >> 16);
}

static __device__ __forceinline__ void gload_lds16(const unsigned short* g, void* l) {
  __builtin_amdgcn_global_load_lds(
      (__attribute__((address_space(1))) void*)(unsigned short*)g,
      (__attribute__((address_space(3))) void*)l, 16, 0, 0);
}

// ---------------- W2 f32 -> bf16 ----------------
__global__ __launch_bounds__(256) void convert_w2_kernel(const float* __restrict__ W2,
                                                         unsigned short* __restrict__ W2b) {
  int q = blockIdx.x * 256 + threadIdx.x;
  const float4 v0 = *(const float4*)(W2 + (size_t)q * 8);
  const float4 v1 = *(const float4*)(W2 + (size_t)q * 8 + 4);
  union { unsigned short s[8]; uint4 u; } o;
  o.s[0] = f2bf(v0.x); o.s[1] = f2bf(v0.y); o.s[2] = f2bf(v0.z); o.s[3] = f2bf(v0.w);
  o.s[4] = f2bf(v1.x); o.s[5] = f2bf(v1.y); o.s[6] = f2bf(v1.z); o.s[7] = f2bf(v1.w);
  *(uint4*)(W2b + (size_t)q * 8) = o.u;
}

// ---------------- proj partials: {ep,dp}{0,1} = X @ W^T over K-half ----------------
// grid = 40: tile_m = bid>>3 (0..4; 4 = dec), kh = (bid>>2)&1, tile_n = bid&3
__global__ __launch_bounds__(256) void proj_kernel(const float* __restrict__ enc,
                                                   const float* __restrict__ dec,
                                                   const float* __restrict__ W1,
                                                   float* __restrict__ ep0,
                                                   float* __restrict__ ep1,
                                                   float* __restrict__ dp0,
                                                   float* __restrict__ dp1) {
  __shared__ unsigned short As[128 * 32];
  __shared__ unsigned short Bs[128 * 32];
  const int tid = threadIdx.x;
  const int tile_m = blockIdx.x >> 3;
  const int kh = (blockIdx.x >> 2) & 1;
  const int tile_n = blockIdx.x & 3;
  const bool is_dec = (tile_m == 4);
  const float* X = is_dec ? dec : enc;
  const int xrow0 = is_dec ? 0 : tile_m * 128;
  const int wcol0 = is_dec ? D_DIM : 0;
  float* outp = is_dec ? (kh ? dp1 : dp0) : (kh ? ep1 : ep0);

  const int lane = tid & 63;
  const int wv = tid >> 6;
  const int wr = wv >> 1, wc = wv & 1;

  const int arow = tid >> 1;
  const int acol = (tid & 1) * 16;

  f32x4 acc[4][4] = {};

  const float* pa = X + (size_t)(xrow0 + arow) * D_DIM + acol;
  const float* pb = W1 + (size_t)(tile_n * 128 + arow) * (2 * D_DIM) + wcol0 + acol;

  for (int k0 = kh * 256; k0 < kh * 256 + 256; k0 += 32) {
    float4 av0 = *(const float4*)(pa + k0);
    float4 av1 = *(const float4*)(pa + k0 + 4);
    float4 av2 = *(const float4*)(pa + k0 + 8);
    float4 av3 = *(const float4*)(pa + k0 + 12);
    float4 bv0 = *(const float4*)(pb + k0);
    float4 bv1 = *(const float4*)(pb + k0 + 4);
    float4 bv2 = *(const float4*)(pb + k0 + 8);
    float4 bv3 = *(const float4*)(pb + k0 + 12);
    __syncthreads();
    union { unsigned short s[8]; uint4 u; } u0, u1, w0, w1;
    u0.s[0] = f2bf(av0.x); u0.s[1] = f2bf(av0.y); u0.s[2] = f2bf(av0.z); u0.s[3] = f2bf(av0.w);
    u0.s[4] = f2bf(av1.x); u0.s[5] = f2bf(av1.y); u0.s[6] = f2bf(av1.z); u0.s[7] = f2bf(av1.w);
    u1.s[0] = f2bf(av2.x); u1.s[1] = f2bf(av2.y); u1.s[2] = f2bf(av2.z); u1.s[3] = f2bf(av2.w);
    u1.s[4] = f2bf(av3.x); u1.s[5] = f2bf(av3.y); u1.s[6] = f2bf(av3.z); u1.s[7] = f2bf(av3.w);
    w0.s[0] = f2bf(bv0.x); w0.s[1] = f2bf(bv0.y); w0.s[2] = f2bf(bv0.z); w0.s[3] = f2bf(bv0.w);
    w0.s[4] = f2bf(bv1.x); w0.s[5] = f2bf(bv1.y); w0.s[6] = f2bf(bv1.z); w0.s[7] = f2bf(bv1.w);
    w1.s[0] = f2bf(bv2.x); w1.s[1] = f2bf(bv2.y); w1.s[2] = f2bf(bv2.z); w1.s[3] = f2bf(bv2.w);
    w1.s[4] = f2bf(bv3.x); w1.s[5] = f2bf(bv3.y); w1.s[6] = f2bf(bv3.z); w1.s[7] = f2bf(bv3.w);
    *(uint4*)&As[arow * 32 + acol] = u0.u;
    *(uint4*)&As[arow * 32 + acol + 8] = u1.u;
    *(uint4*)&Bs[arow * 32 + acol] = w0.u;
    *(uint4*)&Bs[arow * 32 + acol + 8] = w1.u;
    __syncthreads();
    bf16x8 af[4], bff[4];
#pragma unroll
    for (int mi = 0; mi < 4; ++mi)
      af[mi] = *(const bf16x8*)&As[(wr * 64 + mi * 16 + (lane & 15)) * 32 + (lane >> 4) * 8];
#pragma unroll
    for (int ni = 0; ni < 4; ++ni)
      bff[ni] = *(const bf16x8*)&Bs[(wc * 64 + ni * 16 + (lane & 15)) * 32 + (lane >> 4) * 8];
#pragma unroll
    for (int mi = 0; mi < 4; ++mi)
#pragma unroll
      for (int ni = 0; ni < 4; ++ni)
        acc[mi][ni] = __builtin_amdgcn_mfma_f32_16x16x32_bf16(af[mi], bff[ni], acc[mi][ni], 0, 0, 0);
  }

#pragma unroll
  for (int mi = 0; mi < 4; ++mi) {
#pragma unroll
    for (int r = 0; r < 4; ++r) {
      int row = xrow0 + wr * 64 + mi * 16 + ((lane >> 4) << 2) + r;
      float* po = outp + (size_t)row * NIN + tile_n * 128 + wc * 64 + (lane & 15);
#pragma unroll
      for (int ni = 0; ni < 4; ++ni) po[ni * 16] = acc[mi][ni][r];
    }
  }
}

// ---------------- H = tanh(ep0+ep1[bt] + dp0+dp1[bu] + b1) -> bf16 ----------------
__global__ __launch_bounds__(256) void h_kernel(const float* __restrict__ ep0,
                                                const float* __restrict__ ep1,
                                                const float* __restrict__ dp0,
                                                const float* __restrict__ dp1,
                                                const float* __restrict__ b1,
                                                unsigned short* __restrict__ Hb) {
  int q = blockIdx.x * 256 + threadIdx.x;
  int m = q >> 6;
  int i0 = (q & 63) << 3;
  size_t eoff = (size_t)(m >> 6) * NIN + i0;
  size_t doff = (size_t)((m >> 14) * U_DIM + (m & 63)) * NIN + i0;
  float4 e0 = *(const float4*)(ep0 + eoff);
  float4 e1 = *(const float4*)(ep0 + eoff + 4);
  float4 f0 = *(const float4*)(ep1 + eoff);
  float4 f1 = *(const float4*)(ep1 + eoff + 4);
  float4 d0 = *(const float4*)(dp0 + doff);
  float4 d1 = *(const float4*)(dp0 + doff + 4);
  float4 g0 = *(const float4*)(dp1 + doff);
  float4 g1 = *(const float4*)(dp1 + doff + 4);
  float4 c0 = *(const float4*)(b1 + i0);
  float4 c1 = *(const float4*)(b1 + i0 + 4);
  float x[8] = { e0.x + f0.x + d0.x + g0.x + c0.x, e0.y + f0.y + d0.y + g0.y + c0.y,
                 e0.z + f0.z + d0.z + g0.z + c0.z, e0.w + f0.w + d0.w + g0.w + c0.w,
                 e1.x + f1.x + d1.x + g1.x + c1.x, e1.y + f1.y + d1.y + g1.y + c1.y,
                 e1.z + f1.z + d1.z + g1.z + c1.z, e1.w + f1.w + d1.w + g1.w + c1.w };
  union { unsigned short s[8]; uint4 u; } o;
#pragma unroll
  for (int j = 0; j < 8; ++j) {
    float ex = __expf(2.0f * x[j]);
    float t = 1.0f - 2.0f / (ex + 1.0f);
    o.s[j] = f2bf(t);
  }
  *(uint4*)(Hb + (size_t)q * 8) = o.u;
}

// ---------------- main GEMM: out = H @ W2b^T + b2 ----------------
// 256x256 tile, BK=64 (two k-halves of 32), 8 waves (2x4), 8-phase counted-vmcnt.
// LDS swizzle (conflict-free, 2-way): LDS slot (chunk, row r, slot s) holds
// global seg (s - (r>>1)) & 3; read lane (row r'=lane&15, want seg q=lane>>4)
// reads slot (q + (r'>>1)) & 3 -> start banks cover all 8 quads exactly 2x.
__global__ __launch_bounds__(512, 2) void gemm256_kernel(const unsigned short* __restrict__ Hb,
                                                         const unsigned short* __restrict__ W2b,
                                                         const float* __restrict__ b2,
                                                         float* __restrict__ out) {
  __shared__ __align__(16) char smem[131072];
  const int tid = threadIdx.x;
  const int bid = blockIdx.x;
  const int swz = ((bid & 7) << 8) | (bid >> 3);
  const int tile_n = swz & 15, tile_m = swz >> 4;
  const int m0 = tile_m * 256, n0 = tile_n * 256;
  const int lane = tid & 63, w = tid >> 6;
  const int wr = w >> 2, wc = w & 3;

  // staging source (pre-swizzled): lane l covers row (chunk*16 + l>>2),
  // global seg = ((l&3) - (l>>3)) & 3
  const int srow0 = (w << 4) + (lane >> 2);
  const int segp = ((((lane & 3) - ((lane >> 3) & 3)) & 3) << 3);
  const unsigned short* pA0 = Hb + (size_t)(m0 + srow0) * 512 + segp;
  const unsigned short* pA1 = pA0 + 128 * 512;
  const unsigned short* pB0 = W2b + (size_t)(n0 + srow0) * 512 + segp;
  const unsigned short* pB1 = pB0 + 128 * 512;
  const int dstOff = (w << 10) + (lane << 4);  // linear LDS dest
  // swizzled ds_read lane offset: row r'=lane&15, slot = (q + (r'>>1)) & 3
  const int laneA = ((lane & 15) << 6) + ((((lane >> 4) + ((lane >> 1) & 7)) & 3) << 4);
  const int wrOff = wr << 13;
  const int wcOff = wc << 12;

  f32x4 acc[8][4] = {};
  bf16x8 af[8], bq0, bq1;

#define STAGE_A(BUF, KH, T) do { \
    gload_lds16(pA0 + (T) * 64 + (KH) * 32, smem + (BUF) * 32768 + (KH) * 16384 + dstOff); \
    gload_lds16(pA1 + (T) * 64 + (KH) * 32, smem + (BUF) * 32768 + (KH) * 16384 + 8192 + dstOff); \
  } while (0)
#define STAGE_B(BUF, KH, T) do { \
    gload_lds16(pB0 + (T) * 64 + (KH) * 32, smem + 65536 + (BUF) * 32768 + (KH) * 16384 + dstOff); \
    gload_lds16(pB1 + (T) * 64 + (KH) * 32, smem + 65536 + (BUF) * 32768 + (KH) * 16384 + 8192 + dstOff); \
  } while (0)
#define DS_A(BUF, KH, MI) (*(const bf16x8*)(smem + (BUF) * 32768 + (KH) * 16384 + wrOff + (MI) * 1024 + laneA))
#define DS_B(BUF, KH, NI) (*(const bf16x8*)(smem + 65536 + (BUF) * 32768 + (KH) * 16384 + wcOff + (NI) * 1024 + laneA))
#define LD_A(BUF, KH) do { \
    _Pragma("unroll") for (int mi = 0; mi < 8; ++mi) af[mi] = DS_A(BUF, KH, mi); \
  } while (0)
#define QUAD(NH) do { \
    __builtin_amdgcn_s_setprio(1); \
    _Pragma("unroll") for (int mi = 0; mi < 8; ++mi) { \
      acc[mi][2 * (NH)]     = __builtin_amdgcn_mfma_f32_16x16x32_bf16(af[mi], bq0, acc[mi][2 * (NH)], 0, 0, 0); \
      acc[mi][2 * (NH) + 1] = __builtin_amdgcn_mfma_f32_16x16x32_bf16(af[mi], bq1, acc[mi][2 * (NH) + 1], 0, 0, 0); \
    } \
    __builtin_amdgcn_s_setprio(0); \
  } while (0)
#define BAR() __builtin_amdgcn_s_barrier()
#define LGKM0() asm volatile("s_waitcnt lgkmcnt(0)" ::: "memory")
#define VMCNT4() asm volatile("s_waitcnt vmcnt(4)" ::: "memory")
#define VMCNT0() asm volatile("s_waitcnt vmcnt(0)" ::: "memory")

  // prologue
  STAGE_A(0, 0, 0); STAGE_A(0, 1, 0); STAGE_B(0, 0, 0); STAGE_B(0, 1, 0);
  STAGE_A(1, 0, 1); STAGE_B(1, 0, 1);
  VMCNT4();
  BAR();

  for (int i = 0; i < 3; ++i) {
    const int t1 = 2 * i + 1, t2 = 2 * i + 2, t3 = 2 * i + 3;
    LD_A(0, 0); bq0 = DS_B(0, 0, 0); bq1 = DS_B(0, 0, 1);
    STAGE_A(1, 1, t1);
    BAR(); LGKM0(); QUAD(0); BAR();
    bq0 = DS_B(0, 0, 2); bq1 = DS_B(0, 0, 3);
    STAGE_B(1, 1, t1);
    BAR(); LGKM0(); QUAD(1); BAR();
    LD_A(0, 1); bq0 = DS_B(0, 1, 0); bq1 = DS_B(0, 1, 1);
    STAGE_A(0, 0, t2);
    BAR(); LGKM0(); QUAD(0); BAR();
    bq0 = DS_B(0, 1, 2); bq1 = DS_B(0, 1, 3);
    STAGE_B(0, 0, t2);
    VMCNT4();
    BAR(); LGKM0(); QUAD(1); BAR();
    LD_A(1, 0); bq0 = DS_B(1, 0, 0); bq1 = DS_B(1, 0, 1);
    STAGE_A(0, 1, t2);
    BAR(); LGKM0(); QUAD(0); BAR();
    bq0 = DS_B(1, 0, 2); bq1 = DS_B(1, 0, 3);
    STAGE_B(0, 1, t2);
    BAR(); LGKM0(); QUAD(1); BAR();
    LD_A(1, 1); bq0 = DS_B(1, 1, 0); bq1 = DS_B(1, 1, 1);
    STAGE_A(1, 0, t3);
    BAR(); LGKM0(); QUAD(0); BAR();
    bq0 = DS_B(1, 1, 2); bq1 = DS_B(1, 1, 3);
    STAGE_B(1, 0, t3);
    VMCNT4();
    BAR(); LGKM0(); QUAD(1); BAR();
  }

  // tail: tiles 6,7
  LD_A(0, 0); bq0 = DS_B(0, 0, 0); bq1 = DS_B(0, 0, 1);
  STAGE_A(1, 1, 7);
  BAR(); LGKM0(); QUAD(0); BAR();
  bq0 = DS_B(0, 0, 2); bq1 = DS_B(0, 0, 3);
  STAGE_B(1, 1, 7);
  BAR(); LGKM0(); QUAD(1); BAR();
  LD_A(0, 1); bq0 = DS_B(0, 1, 0); bq1 = DS_B(0, 1, 1);
  BAR(); LGKM0(); QUAD(0); BAR();
  bq0 = DS_B(0, 1, 2); bq1 = DS_B(0, 1, 3);
  VMCNT0();
  BAR(); LGKM0(); QUAD(1); BAR();
  LD_A(1, 0); bq0 = DS_B(1, 0, 0); bq1 = DS_B(1, 0, 1);
  BAR(); LGKM0(); QUAD(0); BAR();
  bq0 = DS_B(1, 0, 2); bq1 = DS_B(1, 0, 3);
  BAR(); LGKM0(); QUAD(1); BAR();
  LD_A(1, 1); bq0 = DS_B(1, 1, 0); bq1 = DS_B(1, 1, 1);
  BAR(); LGKM0(); QUAD(0); BAR();
  bq0 = DS_B(1, 1, 2); bq1 = DS_B(1, 1, 3);
  BAR(); LGKM0(); QUAD(1);

  float b2v[4];
#pragma unroll
  for (int ni = 0; ni < 4; ++ni) b2v[ni] = b2[n0 + wc * 64 + ni * 16 + (lane & 15)];
#pragma unroll
  for (int mi = 0; mi < 8; ++mi) {
#pragma unroll
    for (int r = 0; r < 4; ++r) {
      int row = m0 + wr * 128 + mi * 16 + ((lane >> 4) << 2) + r;
      float* po = out + (size_t)row * NV + n0 + wc * 64 + (lane & 15);
#pragma unroll
      for (int ni = 0; ni < 4; ++ni) po[ni * 16] = acc[mi][ni][r] + b2v[ni];
    }
  }
#undef STAGE_A
#undef STAGE_B
#undef DS_A
#undef DS_B
#undef LD_A
#undef QUAD
#undef BAR
#undef LGKM0
#undef VMCNT4
#undef VMCNT0
}

extern "C" void kernel_launch(void* const* d_in, const int* in_sizes, int n_in,
                              void* d_out, int out_size, void* d_ws, size_t ws_size,
                              hipStream_t stream) {
  const float* enc = (const float*)d_in[0];
  const float* dec = (const float*)d_in[1];
  const float* W1  = (const float*)d_in[2];
  const float* b1  = (const float*)d_in[3];
  const float* W2  = (const float*)d_in[4];
  const float* b2  = (const float*)d_in[5];
  float* out = (float*)d_out;

  char* ws = (char*)d_ws;
  unsigned short* W2b = (unsigned short*)(ws);                 // 4 MB
  float* ep0 = (float*)(ws + 4194304);                         // 1 MB
  float* ep1 = (float*)(ws + 5242880);                         // 1 MB
  float* dp0 = (float*)(ws + 6291456);                         // 256 KB
  float* dp1 = (float*)(ws + 6553600);                         // 256 KB
  unsigned short* Hb = (unsigned short*)(ws + 6815744);        // 32 MB

  hipLaunchKernelGGL(convert_w2_kernel, dim3(1024), dim3(256), 0, stream, W2, W2b);
  hipLaunchKernelGGL(proj_kernel, dim3(40), dim3(256), 0, stream, enc, dec, W1, ep0, ep1, dp0, dp1);
  hipLaunchKernelGGL(h_kernel, dim3(8192), dim3(256), 0, stream, ep0, ep1, dp0, dp1, b1, Hb);
  hipLaunchKernelGGL(gemm256_kernel, dim3(2048), dim3(512), 0, stream, Hb, W2b, b2, out);
}